// Round 3
// baseline (172.974 us; speedup 1.0000x reference)
//
#include <hip/hip_runtime.h>
#include <math.h>
#include <stdint.h>

#define NS 200
#define THASH (1 << 19)
#define TMASK ((1u << 19) - 1u)

__device__ __forceinline__ float sigmoidf_(float v) {
    return 1.0f / (1.0f + __expf(-v));
}

// Fused kernel: one block (256 threads) per ray.
// Phase 1: lane s<200 computes label[b,s] (5 levels x 8 corner gathers).
// Phase 2: block-reduce hits (max) and first (min index with label>0.5).
// Phase 3: 240 threads do ONE rgb-table gather each (30 pairs x 8 corners).
// Phase 4: wave 0 runs the 120->64->64->64->3 MLP.
__global__ __launch_bounds__(256) void k_fused(
        const float* __restrict__ x,
        const float* __restrict__ tlab,
        const float* __restrict__ trgb,
        const float* __restrict__ wlab, const float* __restrict__ blab,
        const float* __restrict__ W1, const float* __restrict__ b1,
        const float* __restrict__ W2, const float* __restrict__ b2,
        const float* __restrict__ W3, const float* __restrict__ b3,
        const float* __restrict__ W4, const float* __restrict__ b4,
        float* __restrict__ hits, float* __restrict__ labels,
        float* __restrict__ rgb)
{
    const uint32_t P2 = 2654435761u, P3 = 805459861u;
    const int b = blockIdx.x;
    const int tid = threadIdx.x;
    const int lane = tid & 63;
    const int wid = tid >> 6;
    const float4 ray = *(const float4*)(x + 4 * (size_t)b);

    __shared__ float feat[120];
    __shared__ float hs[64];
    __shared__ float wmax[4];
    __shared__ int wmin[4];
    __shared__ int sfirst;

    // ---- Phase 1: label ----
    float lab = -1.0f;
    int cand = NS;
    if (tid < NS) {
        const float t = (float)tid * (1.0f / 199.0f);
        const float px = ray.x * (1.0f - t) + ray.z * t;
        const float py = ray.y * (1.0f - t) + ray.w * t;
        const float pz = t;

        float acc = blab[0];
        #pragma unroll
        for (int l = 0; l < 5; ++l) {
            const float res = (float)(8 << l);
            const float xf = px * res, yf = py * res, zf = pz * res;
            const float fx = floorf(xf), fy = floorf(yf), fz = floorf(zf);
            const float wx = xf - fx, wy = yf - fy, wz = zf - fz;
            const uint32_t x0 = (uint32_t)(int)fx;
            const uint32_t y0 = (uint32_t)(int)fy;
            const uint32_t z0 = (uint32_t)(int)fz;
            const uint32_t hx0 = x0,       hx1 = x0 + 1u;
            const uint32_t hy0 = y0 * P2,  hy1 = hy0 + P2;
            const uint32_t hz0 = z0 * P3,  hz1 = hz0 + P3;
            const float* __restrict__ tl = tlab + (size_t)l * THASH;
            const float v0 = tl[(hx0 ^ hy0 ^ hz0) & TMASK];
            const float v1 = tl[(hx0 ^ hy0 ^ hz1) & TMASK];
            const float v2 = tl[(hx0 ^ hy1 ^ hz0) & TMASK];
            const float v3 = tl[(hx0 ^ hy1 ^ hz1) & TMASK];
            const float v4 = tl[(hx1 ^ hy0 ^ hz0) & TMASK];
            const float v5 = tl[(hx1 ^ hy0 ^ hz1) & TMASK];
            const float v6 = tl[(hx1 ^ hy1 ^ hz0) & TMASK];
            const float v7 = tl[(hx1 ^ hy1 ^ hz1) & TMASK];
            const float c00 = fmaf(wz, v1 - v0, v0);
            const float c01 = fmaf(wz, v3 - v2, v2);
            const float c10 = fmaf(wz, v5 - v4, v4);
            const float c11 = fmaf(wz, v7 - v6, v6);
            const float c0 = fmaf(wy, c01 - c00, c00);
            const float c1 = fmaf(wy, c11 - c10, c10);
            const float cv = fmaf(wx, c1 - c0, c0);
            acc = fmaf(cv, wlab[l], acc);
        }
        lab = sigmoidf_(acc);
        labels[(size_t)b * NS + tid] = lab;
        if (lab > 0.5f) cand = tid;
    }

    // ---- Phase 2: per-wave shfl reduce, then cross-wave via LDS ----
    float m = lab;
    int c = cand;
    #pragma unroll
    for (int off = 32; off > 0; off >>= 1) {
        m = fmaxf(m, __shfl_xor(m, off));
        c = min(c, __shfl_xor(c, off));
    }
    if (lane == 0) { wmax[wid] = m; wmin[wid] = c; }
    __syncthreads();
    if (tid == 0) {
        float mm = fmaxf(fmaxf(wmax[0], wmax[1]), fmaxf(wmax[2], wmax[3]));
        int cc = min(min(wmin[0], wmin[1]), min(wmin[2], wmin[3]));
        hits[b] = mm;
        sfirst = (cc >= NS) ? 0 : cc;
    }
    __syncthreads();
    const int first = sfirst;

    // ---- Phase 3: rgb encode, one gather per thread (240 active) ----
    const int corner = tid & 7;       // bits 0-2 within wave -> shfl_xor ok
    const int pair = tid >> 3;        // 0..31 (30 used)
    {
        float vx = 0.f, vy = 0.f, vz = 0.f, vw = 0.f;
        if (pair < 30) {
            const int si = pair / 6;
            const int l = pair % 6;
            int sc = first + si - 2;
            sc = sc < 0 ? 0 : (sc > NS - 1 ? NS - 1 : sc);
            const float t = (float)sc * (1.0f / 199.0f);
            const float px = ray.x * (1.0f - t) + ray.z * t;
            const float py = ray.y * (1.0f - t) + ray.w * t;
            const float pz = t;
            const int bi = (corner >> 2) & 1, bj = (corner >> 1) & 1, bk = corner & 1;
            const int res = 4 << l;
            const float xf = px * (float)res, yf = py * (float)res, zf = pz * (float)res;
            const float fx = floorf(xf), fy = floorf(yf), fz = floorf(zf);
            const float wx = xf - fx, wy = yf - fy, wz = zf - fz;
            const uint32_t x0 = (uint32_t)(int)fx, y0 = (uint32_t)(int)fy, z0 = (uint32_t)(int)fz;
            const uint32_t hx = x0 + (uint32_t)bi;
            const uint32_t hy = (y0 + (uint32_t)bj) * P2;
            const uint32_t hz = (z0 + (uint32_t)bk) * P3;
            const uint32_t idx = (hx ^ hy ^ hz) & TMASK;
            const float cw = (bi ? wx : 1.0f - wx) * (bj ? wy : 1.0f - wy) * (bk ? wz : 1.0f - wz);
            const float4 tv = *(const float4*)(trgb + (((size_t)l << 19) + idx) * 4);
            vx = tv.x * cw; vy = tv.y * cw; vz = tv.z * cw; vw = tv.w * cw;
        }
        #pragma unroll
        for (int mm = 1; mm < 8; mm <<= 1) {
            vx += __shfl_xor(vx, mm);
            vy += __shfl_xor(vy, mm);
            vz += __shfl_xor(vz, mm);
            vw += __shfl_xor(vw, mm);
        }
        if (corner == 0 && pair < 30) {
            const int si = pair / 6, l = pair % 6;
            float* f = &feat[si * 24 + l * 4];
            f[0] = vx; f[1] = vy; f[2] = vz; f[3] = vw;
        }
    }
    __syncthreads();

    // ---- Phase 4: MLP on wave 0 only (no __syncthreads below) ----
    if (wid == 0) {
        float a0 = b1[lane], a1 = 0.f, a2 = 0.f, a3 = 0.f;
        #pragma unroll
        for (int i = 0; i < 120; i += 4) {
            const float4 fv = *(const float4*)(feat + i);
            a0 = fmaf(fv.x, W1[(i + 0) * 64 + lane], a0);
            a1 = fmaf(fv.y, W1[(i + 1) * 64 + lane], a1);
            a2 = fmaf(fv.z, W1[(i + 2) * 64 + lane], a2);
            a3 = fmaf(fv.w, W1[(i + 3) * 64 + lane], a3);
        }
        float h = fmaxf((a0 + a1) + (a2 + a3), 0.0f);

        hs[lane] = h;  // wave-local LDS: lgkmcnt handles ordering
        a0 = b2[lane]; a1 = 0.f; a2 = 0.f; a3 = 0.f;
        #pragma unroll
        for (int i = 0; i < 64; i += 4) {
            const float4 hv = *(const float4*)(hs + i);
            a0 = fmaf(hv.x, W2[(i + 0) * 64 + lane], a0);
            a1 = fmaf(hv.y, W2[(i + 1) * 64 + lane], a1);
            a2 = fmaf(hv.z, W2[(i + 2) * 64 + lane], a2);
            a3 = fmaf(hv.w, W2[(i + 3) * 64 + lane], a3);
        }
        h = fmaxf((a0 + a1) + (a2 + a3), 0.0f);

        // avoid RAW hazard on hs across the wave without syncthreads:
        // all 64 lanes write then read only after lgkmcnt drain; within a
        // single wave lockstep this is safe (write completes before read issues
        // in program order per-lane, and cross-lane reads happen after the
        // compiler-inserted lgkmcnt(0) on the ds_write).
        __builtin_amdgcn_s_waitcnt(0);  // belt & suspenders: drain lgkm
        hs[lane] = h;
        a0 = b3[lane]; a1 = 0.f; a2 = 0.f; a3 = 0.f;
        #pragma unroll
        for (int i = 0; i < 64; i += 4) {
            const float4 hv = *(const float4*)(hs + i);
            a0 = fmaf(hv.x, W3[(i + 0) * 64 + lane], a0);
            a1 = fmaf(hv.y, W3[(i + 1) * 64 + lane], a1);
            a2 = fmaf(hv.z, W3[(i + 2) * 64 + lane], a2);
            a3 = fmaf(hv.w, W3[(i + 3) * 64 + lane], a3);
        }
        h = fmaxf((a0 + a1) + (a2 + a3), 0.0f);

        __builtin_amdgcn_s_waitcnt(0);
        hs[lane] = h;
        if (lane < 3) {
            float r = b4[lane];
            #pragma unroll 8
            for (int j = 0; j < 64; ++j) r = fmaf(hs[j], W4[j * 3 + lane], r);
            rgb[(size_t)b * 3 + lane] = r;
        }
    }
}

extern "C" void kernel_launch(void* const* d_in, const int* in_sizes, int n_in,
                              void* d_out, int out_size, void* d_ws, size_t ws_size,
                              hipStream_t stream) {
    const float* x    = (const float*)d_in[0];
    const float* tlab = (const float*)d_in[1];
    const float* trgb = (const float*)d_in[2];
    const float* wlab = (const float*)d_in[3];
    const float* blab = (const float*)d_in[4];
    const float* W1   = (const float*)d_in[5];
    const float* b1   = (const float*)d_in[6];
    const float* W2   = (const float*)d_in[7];
    const float* b2   = (const float*)d_in[8];
    const float* W3   = (const float*)d_in[9];
    const float* b3   = (const float*)d_in[10];
    const float* W4   = (const float*)d_in[11];
    const float* b4   = (const float*)d_in[12];

    const int B = in_sizes[0] / 4;  // 16384

    float* hits   = (float*)d_out;                       // [B]
    float* labels = hits + B;                            // [B*NS]
    float* rgbout = labels + (size_t)B * NS;             // [B*3]

    k_fused<<<B, 256, 0, stream>>>(x, tlab, trgb, wlab, blab,
                                   W1, b1, W2, b2, W3, b3, W4, b4,
                                   hits, labels, rgbout);
}

// Round 4
// 120.454 us; speedup vs baseline: 1.4360x; 1.4360x over previous
//
#include <hip/hip_runtime.h>
#include <math.h>
#include <stdint.h>

#define NS 200
#define THASH (1 << 19)
#define TMASK ((1u << 19) - 1u)

__device__ __forceinline__ float sigmoidf_(float v) {
    return 1.0f / (1.0f + __expf(-v));
}

// Kernel 1: one block (256 threads) per ray; lane s = sample s.
// Within-wave gather dedup: consecutive samples sharing a grid cell fetch
// the 8 corner values once (run leader) and broadcast via bpermute.
__global__ __launch_bounds__(256) void k_label(
        const float* __restrict__ x,
        const float* __restrict__ tlab,
        const float* __restrict__ wlab, const float* __restrict__ blab,
        float* __restrict__ hits, float* __restrict__ labels,
        int* __restrict__ firsts)
{
    const uint32_t P2 = 2654435761u, P3 = 805459861u;
    const int b = blockIdx.x;
    const int tid = threadIdx.x;
    const int lane = tid & 63;
    const int wid = tid >> 6;
    const float4 ray = *(const float4*)(x + 4 * (size_t)b);

    // threads >= NS compute a clamped duplicate of sample 199 (never leaders
    // in their run except trivially; results discarded).
    const int s_eff = tid < NS ? tid : NS - 1;
    const float t = (float)s_eff * (1.0f / 199.0f);
    const float px = ray.x * (1.0f - t) + ray.z * t;
    const float py = ray.y * (1.0f - t) + ray.w * t;
    const float pz = t;

    float acc = blab[0];
    #pragma unroll
    for (int l = 0; l < 5; ++l) {
        const float res = (float)(8 << l);
        const float xf = px * res, yf = py * res, zf = pz * res;
        const float fx = floorf(xf), fy = floorf(yf), fz = floorf(zf);
        const float wx = xf - fx, wy = yf - fy, wz = zf - fz;
        const uint32_t x0 = (uint32_t)(int)fx;
        const uint32_t y0 = (uint32_t)(int)fy;
        const uint32_t z0 = (uint32_t)(int)fz;

        // run-leader detection (cell coords fit in 10 bits each: res<=128 -> <=129)
        const uint32_t cell = x0 | (y0 << 10) | (z0 << 20);
        const uint32_t prevc = __shfl_up(cell, 1);
        const bool leader = (lane == 0) || (prevc != cell);
        const uint64_t bal = __ballot(leader);
        const uint64_t below = bal & (~0ull >> (63 - lane));
        const int ldr = 63 - __clzll(below);

        float v0 = 0.f, v1 = 0.f, v2 = 0.f, v3 = 0.f,
              v4 = 0.f, v5 = 0.f, v6 = 0.f, v7 = 0.f;
        if (leader) {
            const uint32_t hx0 = x0,      hx1 = x0 + 1u;
            const uint32_t hy0 = y0 * P2, hy1 = hy0 + P2;
            const uint32_t hz0 = z0 * P3, hz1 = hz0 + P3;
            const float* __restrict__ tl = tlab + (size_t)l * THASH;
            v0 = tl[(hx0 ^ hy0 ^ hz0) & TMASK];
            v1 = tl[(hx0 ^ hy0 ^ hz1) & TMASK];
            v2 = tl[(hx0 ^ hy1 ^ hz0) & TMASK];
            v3 = tl[(hx0 ^ hy1 ^ hz1) & TMASK];
            v4 = tl[(hx1 ^ hy0 ^ hz0) & TMASK];
            v5 = tl[(hx1 ^ hy0 ^ hz1) & TMASK];
            v6 = tl[(hx1 ^ hy1 ^ hz0) & TMASK];
            v7 = tl[(hx1 ^ hy1 ^ hz1) & TMASK];
        }
        v0 = __shfl(v0, ldr); v1 = __shfl(v1, ldr);
        v2 = __shfl(v2, ldr); v3 = __shfl(v3, ldr);
        v4 = __shfl(v4, ldr); v5 = __shfl(v5, ldr);
        v6 = __shfl(v6, ldr); v7 = __shfl(v7, ldr);

        const float c00 = fmaf(wz, v1 - v0, v0);
        const float c01 = fmaf(wz, v3 - v2, v2);
        const float c10 = fmaf(wz, v5 - v4, v4);
        const float c11 = fmaf(wz, v7 - v6, v6);
        const float c0 = fmaf(wy, c01 - c00, c00);
        const float c1 = fmaf(wy, c11 - c10, c10);
        const float cv = fmaf(wx, c1 - c0, c0);
        acc = fmaf(cv, wlab[l], acc);
    }

    float lab = -1.0f;
    int cand = NS;
    if (tid < NS) {
        lab = sigmoidf_(acc);
        labels[(size_t)b * NS + tid] = lab;
        if (lab > 0.5f) cand = tid;
    }

    // ---- block reduce: max(label), min(first idx > 0.5) ----
    __shared__ float wmax[4];
    __shared__ int wmin[4];
    float m = lab;
    int c = cand;
    #pragma unroll
    for (int off = 32; off > 0; off >>= 1) {
        m = fmaxf(m, __shfl_xor(m, off));
        c = min(c, __shfl_xor(c, off));
    }
    if (lane == 0) { wmax[wid] = m; wmin[wid] = c; }
    __syncthreads();
    if (tid == 0) {
        float mm = fmaxf(fmaxf(wmax[0], wmax[1]), fmaxf(wmax[2], wmax[3]));
        int cc = min(min(wmin[0], wmin[1]), min(wmin[2], wmin[3]));
        hits[b] = mm;
        firsts[b] = (cc >= NS) ? 0 : cc;
    }
}

// Kernel 2: 256 threads = 4 waves; each wave handles one ray.
__global__ __launch_bounds__(256) void k_rgb(
        const float* __restrict__ x,
        const float* __restrict__ trgb,
        const int* __restrict__ firsts,
        const float* __restrict__ W1, const float* __restrict__ b1,
        const float* __restrict__ W2, const float* __restrict__ b2,
        const float* __restrict__ W3, const float* __restrict__ b3,
        const float* __restrict__ W4, const float* __restrict__ b4,
        float* __restrict__ rgb)
{
    const uint32_t P2 = 2654435761u, P3 = 805459861u;
    const int wid = threadIdx.x >> 6;
    const int lane = threadIdx.x & 63;
    const int b = blockIdx.x * 4 + wid;

    __shared__ float feat[4][120];
    __shared__ float hs[4][64];

    const float4 ray = *(const float4*)(x + 4 * (size_t)b);
    const int first = firsts[b];

    const int corner = lane & 7;
    const int group = lane >> 3;
    const int bi = (corner >> 2) & 1, bj = (corner >> 1) & 1, bk = corner & 1;

    #pragma unroll
    for (int it = 0; it < 4; ++it) {
        const int pair = it * 8 + group;  // 0..31 (30 used)
        float vx = 0.f, vy = 0.f, vz = 0.f, vw = 0.f;
        if (pair < 30) {
            const int si = pair / 6;
            const int l = pair % 6;
            int sc = first + si - 2;
            sc = sc < 0 ? 0 : (sc > NS - 1 ? NS - 1 : sc);
            const float t = (float)sc * (1.0f / 199.0f);
            const float px = ray.x * (1.0f - t) + ray.z * t;
            const float py = ray.y * (1.0f - t) + ray.w * t;
            const float pz = t;
            const int res = 4 << l;
            const float xf = px * (float)res, yf = py * (float)res, zf = pz * (float)res;
            const float fx = floorf(xf), fy = floorf(yf), fz = floorf(zf);
            const float wx = xf - fx, wy = yf - fy, wz = zf - fz;
            const uint32_t x0 = (uint32_t)(int)fx, y0 = (uint32_t)(int)fy, z0 = (uint32_t)(int)fz;
            const uint32_t hx = x0 + (uint32_t)bi;
            const uint32_t hy = (y0 + (uint32_t)bj) * P2;
            const uint32_t hz = (z0 + (uint32_t)bk) * P3;
            const uint32_t idx = (hx ^ hy ^ hz) & TMASK;
            const float cw = (bi ? wx : 1.0f - wx) * (bj ? wy : 1.0f - wy) * (bk ? wz : 1.0f - wz);
            const float4 tv = *(const float4*)(trgb + (((size_t)l << 19) + idx) * 4);
            vx = tv.x * cw; vy = tv.y * cw; vz = tv.z * cw; vw = tv.w * cw;
        }
        #pragma unroll
        for (int m = 1; m < 8; m <<= 1) {
            vx += __shfl_xor(vx, m);
            vy += __shfl_xor(vy, m);
            vz += __shfl_xor(vz, m);
            vw += __shfl_xor(vw, m);
        }
        if (corner == 0 && pair < 30) {
            const int si = pair / 6, l = pair % 6;
            float* f = &feat[wid][si * 24 + l * 4];
            f[0] = vx; f[1] = vy; f[2] = vz; f[3] = vw;
        }
    }
    __syncthreads();

    // ---- MLP layer 1 (120 -> 64) ----
    const float* fw = feat[wid];
    float a0 = b1[lane], a1 = 0.f, a2 = 0.f, a3 = 0.f;
    #pragma unroll
    for (int i = 0; i < 120; i += 4) {
        const float4 fv = *(const float4*)(fw + i);
        a0 = fmaf(fv.x, W1[(i + 0) * 64 + lane], a0);
        a1 = fmaf(fv.y, W1[(i + 1) * 64 + lane], a1);
        a2 = fmaf(fv.z, W1[(i + 2) * 64 + lane], a2);
        a3 = fmaf(fv.w, W1[(i + 3) * 64 + lane], a3);
    }
    float h = fmaxf((a0 + a1) + (a2 + a3), 0.0f);

    // ---- layer 2 (64 -> 64) ----
    hs[wid][lane] = h;
    __syncthreads();
    a0 = b2[lane]; a1 = 0.f; a2 = 0.f; a3 = 0.f;
    #pragma unroll
    for (int i = 0; i < 64; i += 4) {
        const float4 hv = *(const float4*)(&hs[wid][i]);
        a0 = fmaf(hv.x, W2[(i + 0) * 64 + lane], a0);
        a1 = fmaf(hv.y, W2[(i + 1) * 64 + lane], a1);
        a2 = fmaf(hv.z, W2[(i + 2) * 64 + lane], a2);
        a3 = fmaf(hv.w, W2[(i + 3) * 64 + lane], a3);
    }
    h = fmaxf((a0 + a1) + (a2 + a3), 0.0f);

    // ---- layer 3 (64 -> 64) ----
    __syncthreads();
    hs[wid][lane] = h;
    __syncthreads();
    a0 = b3[lane]; a1 = 0.f; a2 = 0.f; a3 = 0.f;
    #pragma unroll
    for (int i = 0; i < 64; i += 4) {
        const float4 hv = *(const float4*)(&hs[wid][i]);
        a0 = fmaf(hv.x, W3[(i + 0) * 64 + lane], a0);
        a1 = fmaf(hv.y, W3[(i + 1) * 64 + lane], a1);
        a2 = fmaf(hv.z, W3[(i + 2) * 64 + lane], a2);
        a3 = fmaf(hv.w, W3[(i + 3) * 64 + lane], a3);
    }
    h = fmaxf((a0 + a1) + (a2 + a3), 0.0f);

    // ---- layer 4 (64 -> 3) ----
    __syncthreads();
    hs[wid][lane] = h;
    __syncthreads();
    if (lane < 3) {
        float r = b4[lane];
        #pragma unroll 8
        for (int j = 0; j < 64; ++j) r = fmaf(hs[wid][j], W4[j * 3 + lane], r);
        rgb[(size_t)b * 3 + lane] = r;
    }
}

extern "C" void kernel_launch(void* const* d_in, const int* in_sizes, int n_in,
                              void* d_out, int out_size, void* d_ws, size_t ws_size,
                              hipStream_t stream) {
    const float* x    = (const float*)d_in[0];
    const float* tlab = (const float*)d_in[1];
    const float* trgb = (const float*)d_in[2];
    const float* wlab = (const float*)d_in[3];
    const float* blab = (const float*)d_in[4];
    const float* W1   = (const float*)d_in[5];
    const float* b1   = (const float*)d_in[6];
    const float* W2   = (const float*)d_in[7];
    const float* b2   = (const float*)d_in[8];
    const float* W3   = (const float*)d_in[9];
    const float* b3   = (const float*)d_in[10];
    const float* W4   = (const float*)d_in[11];
    const float* b4   = (const float*)d_in[12];

    const int B = in_sizes[0] / 4;  // 16384

    float* hits   = (float*)d_out;                       // [B]
    float* labels = hits + B;                            // [B*NS]
    float* rgbout = labels + (size_t)B * NS;             // [B*3]
    int* firsts   = (int*)d_ws;                          // [B]

    k_label<<<B, 256, 0, stream>>>(x, tlab, wlab, blab, hits, labels, firsts);
    k_rgb<<<B / 4, 256, 0, stream>>>(x, trgb, firsts,
                                     W1, b1, W2, b2, W3, b3, W4, b4, rgbout);
}

// Round 5
// 106.161 us; speedup vs baseline: 1.6293x; 1.1346x over previous
//
#include <hip/hip_runtime.h>
#include <math.h>
#include <stdint.h>

#define NS 200
#define THASH (1 << 19)
#define TMASK ((1u << 19) - 1u)

__device__ __forceinline__ float sigmoidf_(float v) {
    return 1.0f / (1.0f + __expf(-v));
}

// Kernel 1: one block (256 threads) per ray; lane s = sample s.
// Dedup via run-leaders; leader detection from a single packed shfl_up at the
// finest resolution (coarser cells are right-shifts of the finest cell).
__global__ __launch_bounds__(256) void k_label(
        const float* __restrict__ x,
        const float* __restrict__ tlab,
        const float* __restrict__ wlab, const float* __restrict__ blab,
        float* __restrict__ hits, float* __restrict__ labels,
        int* __restrict__ firsts)
{
    const uint32_t P2 = 2654435761u, P3 = 805459861u;
    const int b = blockIdx.x;
    const int tid = threadIdx.x;
    const int lane = tid & 63;
    const int wid = tid >> 6;
    const float4 ray = *(const float4*)(x + 4 * (size_t)b);

    const int s_eff = tid < NS ? tid : NS - 1;
    const float t = (float)s_eff * (1.0f / 199.0f);
    const float px = ray.x * (1.0f - t) + ray.z * t;
    const float py = ray.y * (1.0f - t) + ray.w * t;
    const float pz = t;

    // finest level (res = 128) coordinates; coarser levels derived by shifts
    const float xf4 = px * 128.0f, yf4 = py * 128.0f, zf4 = pz * 128.0f;
    const float fx4 = floorf(xf4), fy4 = floorf(yf4), fz4 = floorf(zf4);
    const uint32_t x4 = (uint32_t)(int)fx4;
    const uint32_t y4 = (uint32_t)(int)fy4;
    const uint32_t z4 = (uint32_t)(int)fz4;
    const uint32_t cell4 = x4 | (y4 << 10) | (z4 << 20);
    const uint32_t prev = __shfl_up(cell4, 1);
    const uint32_t diff = cell4 ^ prev;   // garbage at lane 0 (forced leader)

    float acc = blab[0];

    // ---- levels 0..3 with run-dedup ----
    #pragma unroll
    for (int l = 0; l < 4; ++l) {
        const int k = 4 - l;
        const uint32_t fm = 0x3FFu & ~((1u << k) - 1u);
        const uint32_t m_l = fm | (fm << 10) | (fm << 20);
        const bool leader = (lane == 0) || ((diff & m_l) != 0u);
        const uint64_t bal = __ballot(leader);
        const uint64_t below = bal & (~0ull >> (63 - lane));
        const int ldr = 63 - __clzll(below);

        const uint32_t x0 = x4 >> k, y0 = y4 >> k, z0 = z4 >> k;
        const float sc = 1.0f / (float)(1 << k);     // exact 2^-k
        const float wx = fmaf(xf4, sc, -(float)x0);
        const float wy = fmaf(yf4, sc, -(float)y0);
        const float wz = fmaf(zf4, sc, -(float)z0);

        float v0 = 0.f, v1 = 0.f, v2 = 0.f, v3 = 0.f,
              v4v = 0.f, v5 = 0.f, v6 = 0.f, v7 = 0.f;
        if (leader) {
            const uint32_t hy0 = y0 * P2, hz0 = z0 * P3;
            const uint32_t base = x0 ^ hy0 ^ hz0;
            const uint32_t dx = x0 ^ (x0 + 1u);
            const uint32_t dy = hy0 ^ (hy0 + P2);
            const uint32_t dz = hz0 ^ (hz0 + P3);
            const float* __restrict__ tl = tlab + (size_t)l * THASH;
            v0  = tl[ base                 & TMASK];
            v1  = tl[(base ^ dz)           & TMASK];
            v2  = tl[(base ^ dy)           & TMASK];
            v3  = tl[(base ^ dy ^ dz)      & TMASK];
            v4v = tl[(base ^ dx)           & TMASK];
            v5  = tl[(base ^ dx ^ dz)      & TMASK];
            v6  = tl[(base ^ dx ^ dy)      & TMASK];
            v7  = tl[(base ^ dx ^ dy ^ dz) & TMASK];
        }
        v0  = __shfl(v0, ldr);  v1 = __shfl(v1, ldr);
        v2  = __shfl(v2, ldr);  v3 = __shfl(v3, ldr);
        v4v = __shfl(v4v, ldr); v5 = __shfl(v5, ldr);
        v6  = __shfl(v6, ldr);  v7 = __shfl(v7, ldr);

        const float c00 = fmaf(wz, v1 - v0, v0);
        const float c01 = fmaf(wz, v3 - v2, v2);
        const float c10 = fmaf(wz, v5 - v4v, v4v);
        const float c11 = fmaf(wz, v7 - v6, v6);
        const float c0 = fmaf(wy, c01 - c00, c00);
        const float c1 = fmaf(wy, c11 - c10, c10);
        const float cv = fmaf(wx, c1 - c0, c0);
        acc = fmaf(cv, wlab[l], acc);
    }

    // ---- level 4 (res=128): runs are ~1 sample, fetch directly ----
    {
        const float wx = xf4 - fx4, wy = yf4 - fy4, wz = zf4 - fz4;
        const uint32_t hy0 = y4 * P2, hz0 = z4 * P3;
        const uint32_t base = x4 ^ hy0 ^ hz0;
        const uint32_t dx = x4 ^ (x4 + 1u);
        const uint32_t dy = hy0 ^ (hy0 + P2);
        const uint32_t dz = hz0 ^ (hz0 + P3);
        const float* __restrict__ tl = tlab + (size_t)4 * THASH;
        const float v0  = tl[ base                 & TMASK];
        const float v1  = tl[(base ^ dz)           & TMASK];
        const float v2  = tl[(base ^ dy)           & TMASK];
        const float v3  = tl[(base ^ dy ^ dz)      & TMASK];
        const float v4v = tl[(base ^ dx)           & TMASK];
        const float v5  = tl[(base ^ dx ^ dz)      & TMASK];
        const float v6  = tl[(base ^ dx ^ dy)      & TMASK];
        const float v7  = tl[(base ^ dx ^ dy ^ dz) & TMASK];
        const float c00 = fmaf(wz, v1 - v0, v0);
        const float c01 = fmaf(wz, v3 - v2, v2);
        const float c10 = fmaf(wz, v5 - v4v, v4v);
        const float c11 = fmaf(wz, v7 - v6, v6);
        const float c0 = fmaf(wy, c01 - c00, c00);
        const float c1 = fmaf(wy, c11 - c10, c10);
        const float cv = fmaf(wx, c1 - c0, c0);
        acc = fmaf(cv, wlab[4], acc);
    }

    float lab = -1.0f;
    int cand = NS;
    if (tid < NS) {
        lab = sigmoidf_(acc);
        labels[(size_t)b * NS + tid] = lab;
        if (lab > 0.5f) cand = tid;
    }

    // ---- block reduce: max(label), min(first idx > 0.5) ----
    __shared__ float wmax[4];
    __shared__ int wmin[4];
    float m = lab;
    int c = cand;
    #pragma unroll
    for (int off = 32; off > 0; off >>= 1) {
        m = fmaxf(m, __shfl_xor(m, off));
        c = min(c, __shfl_xor(c, off));
    }
    if (lane == 0) { wmax[wid] = m; wmin[wid] = c; }
    __syncthreads();
    if (tid == 0) {
        float mm = fmaxf(fmaxf(wmax[0], wmax[1]), fmaxf(wmax[2], wmax[3]));
        int cc = min(min(wmin[0], wmin[1]), min(wmin[2], wmin[3]));
        hits[b] = mm;
        firsts[b] = (cc >= NS) ? 0 : cc;
    }
}

// Kernel 2: 1024 blocks x 16 rays. Phase A: 15 iters of one gather/thread
// (16 rays x 8 corners = 256 lanes per iter) -> feat[16][120] in LDS.
// Phase B: each wave runs the MLP for 4 rays (weights loaded once per wave
// per element, reused x4 -> W traffic 1GB -> 64MB).
#define RPB 16
__global__ __launch_bounds__(256) void k_rgb(
        const float* __restrict__ x,
        const float* __restrict__ trgb,
        const int* __restrict__ firsts,
        const float* __restrict__ W1, const float* __restrict__ b1,
        const float* __restrict__ W2, const float* __restrict__ b2,
        const float* __restrict__ W3, const float* __restrict__ b3,
        const float* __restrict__ W4, const float* __restrict__ b4,
        float* __restrict__ rgb)
{
    const uint32_t P2 = 2654435761u, P3 = 805459861u;
    const int tid = threadIdx.x;
    const int lane = tid & 63;
    const int wid = tid >> 6;
    const int rayBase = blockIdx.x * RPB;

    __shared__ float feat[RPB][120];
    __shared__ float hs[RPB][64];

    // ---- Phase A: feature gather ----
    const int corner = tid & 7;
    const int rp = tid >> 3;          // 0..31 = (ray, pair-half)
    const int ray = rp >> 1;
    const int pairHalf = rp & 1;
    const int bi = (corner >> 2) & 1, bj = (corner >> 1) & 1, bk = corner & 1;

    const float4 rd = *(const float4*)(x + 4 * (size_t)(rayBase + ray));
    const int first = firsts[rayBase + ray];

    #pragma unroll
    for (int it = 0; it < 15; ++it) {
        const int pair = pairHalf * 15 + it;   // 0..29
        const int si = pair / 6;
        const int l = pair % 6;
        int scl = first + si - 2;
        scl = scl < 0 ? 0 : (scl > NS - 1 ? NS - 1 : scl);
        const float t = (float)scl * (1.0f / 199.0f);
        const float px = rd.x * (1.0f - t) + rd.z * t;
        const float py = rd.y * (1.0f - t) + rd.w * t;
        const float pz = t;
        const int res = 4 << l;
        const float xf = px * (float)res, yf = py * (float)res, zf = pz * (float)res;
        const float fx = floorf(xf), fy = floorf(yf), fz = floorf(zf);
        const float wx = xf - fx, wy = yf - fy, wz = zf - fz;
        const uint32_t x0 = (uint32_t)(int)fx, y0 = (uint32_t)(int)fy, z0 = (uint32_t)(int)fz;
        const uint32_t hx = x0 + (uint32_t)bi;
        const uint32_t hy = (y0 + (uint32_t)bj) * P2;
        const uint32_t hz = (z0 + (uint32_t)bk) * P3;
        const uint32_t idx = (hx ^ hy ^ hz) & TMASK;
        const float cw = (bi ? wx : 1.0f - wx) * (bj ? wy : 1.0f - wy) * (bk ? wz : 1.0f - wz);
        const float4 tv = *(const float4*)(trgb + (((size_t)l << 19) + idx) * 4);
        float vx = tv.x * cw, vy = tv.y * cw, vz = tv.z * cw, vw = tv.w * cw;
        #pragma unroll
        for (int mm = 1; mm < 8; mm <<= 1) {
            vx += __shfl_xor(vx, mm);
            vy += __shfl_xor(vy, mm);
            vz += __shfl_xor(vz, mm);
            vw += __shfl_xor(vw, mm);
        }
        if (corner == 0) {
            float* f = &feat[ray][si * 24 + l * 4];
            f[0] = vx; f[1] = vy; f[2] = vz; f[3] = vw;
        }
    }
    __syncthreads();

    // ---- Phase B: MLP, 4 rays per wave ----
    const int r0 = wid * 4;

    // layer 1: 120 -> 64
    float a0 = b1[lane], a1 = a0, a2 = a0, a3 = a0;
    #pragma unroll 6
    for (int i = 0; i < 120; i += 4) {
        const float4 f0 = *(const float4*)(&feat[r0 + 0][i]);
        const float4 f1 = *(const float4*)(&feat[r0 + 1][i]);
        const float4 f2 = *(const float4*)(&feat[r0 + 2][i]);
        const float4 f3 = *(const float4*)(&feat[r0 + 3][i]);
        #pragma unroll
        for (int j = 0; j < 4; ++j) {
            const float wv = W1[(i + j) * 64 + lane];
            a0 = fmaf(((const float*)&f0)[j], wv, a0);
            a1 = fmaf(((const float*)&f1)[j], wv, a1);
            a2 = fmaf(((const float*)&f2)[j], wv, a2);
            a3 = fmaf(((const float*)&f3)[j], wv, a3);
        }
    }
    hs[r0 + 0][lane] = fmaxf(a0, 0.f);
    hs[r0 + 1][lane] = fmaxf(a1, 0.f);
    hs[r0 + 2][lane] = fmaxf(a2, 0.f);
    hs[r0 + 3][lane] = fmaxf(a3, 0.f);
    __syncthreads();

    // layer 2: 64 -> 64
    a0 = b2[lane]; a1 = a0; a2 = a0; a3 = a0;
    #pragma unroll 4
    for (int i = 0; i < 64; i += 4) {
        const float4 f0 = *(const float4*)(&hs[r0 + 0][i]);
        const float4 f1 = *(const float4*)(&hs[r0 + 1][i]);
        const float4 f2 = *(const float4*)(&hs[r0 + 2][i]);
        const float4 f3 = *(const float4*)(&hs[r0 + 3][i]);
        #pragma unroll
        for (int j = 0; j < 4; ++j) {
            const float wv = W2[(i + j) * 64 + lane];
            a0 = fmaf(((const float*)&f0)[j], wv, a0);
            a1 = fmaf(((const float*)&f1)[j], wv, a1);
            a2 = fmaf(((const float*)&f2)[j], wv, a2);
            a3 = fmaf(((const float*)&f3)[j], wv, a3);
        }
    }
    __syncthreads();
    hs[r0 + 0][lane] = fmaxf(a0, 0.f);
    hs[r0 + 1][lane] = fmaxf(a1, 0.f);
    hs[r0 + 2][lane] = fmaxf(a2, 0.f);
    hs[r0 + 3][lane] = fmaxf(a3, 0.f);
    __syncthreads();

    // layer 3: 64 -> 64
    a0 = b3[lane]; a1 = a0; a2 = a0; a3 = a0;
    #pragma unroll 4
    for (int i = 0; i < 64; i += 4) {
        const float4 f0 = *(const float4*)(&hs[r0 + 0][i]);
        const float4 f1 = *(const float4*)(&hs[r0 + 1][i]);
        const float4 f2 = *(const float4*)(&hs[r0 + 2][i]);
        const float4 f3 = *(const float4*)(&hs[r0 + 3][i]);
        #pragma unroll
        for (int j = 0; j < 4; ++j) {
            const float wv = W3[(i + j) * 64 + lane];
            a0 = fmaf(((const float*)&f0)[j], wv, a0);
            a1 = fmaf(((const float*)&f1)[j], wv, a1);
            a2 = fmaf(((const float*)&f2)[j], wv, a2);
            a3 = fmaf(((const float*)&f3)[j], wv, a3);
        }
    }
    __syncthreads();
    hs[r0 + 0][lane] = fmaxf(a0, 0.f);
    hs[r0 + 1][lane] = fmaxf(a1, 0.f);
    hs[r0 + 2][lane] = fmaxf(a2, 0.f);
    hs[r0 + 3][lane] = fmaxf(a3, 0.f);
    __syncthreads();

    // layer 4: 64 -> 3 (lanes 0..11 = ray*3+channel)
    if (lane < 12) {
        const int r = lane / 3, ch = lane % 3;
        float acc = b4[ch];
        #pragma unroll 8
        for (int j = 0; j < 64; ++j)
            acc = fmaf(hs[r0 + r][j], W4[j * 3 + ch], acc);
        rgb[(size_t)(rayBase + r0 + r) * 3 + ch] = acc;
    }
}

extern "C" void kernel_launch(void* const* d_in, const int* in_sizes, int n_in,
                              void* d_out, int out_size, void* d_ws, size_t ws_size,
                              hipStream_t stream) {
    const float* x    = (const float*)d_in[0];
    const float* tlab = (const float*)d_in[1];
    const float* trgb = (const float*)d_in[2];
    const float* wlab = (const float*)d_in[3];
    const float* blab = (const float*)d_in[4];
    const float* W1   = (const float*)d_in[5];
    const float* b1   = (const float*)d_in[6];
    const float* W2   = (const float*)d_in[7];
    const float* b2   = (const float*)d_in[8];
    const float* W3   = (const float*)d_in[9];
    const float* b3   = (const float*)d_in[10];
    const float* W4   = (const float*)d_in[11];
    const float* b4   = (const float*)d_in[12];

    const int B = in_sizes[0] / 4;  // 16384

    float* hits   = (float*)d_out;                       // [B]
    float* labels = hits + B;                            // [B*NS]
    float* rgbout = labels + (size_t)B * NS;             // [B*3]
    int* firsts   = (int*)d_ws;                          // [B]

    k_label<<<B, 256, 0, stream>>>(x, tlab, wlab, blab, hits, labels, firsts);
    k_rgb<<<B / RPB, 256, 0, stream>>>(x, trgb, firsts,
                                       W1, b1, W2, b2, W3, b3, W4, b4, rgbout);
}